// Round 1
// baseline (304.970 us; speedup 1.0000x reference)
//
#include <hip/hip_runtime.h>
#include <math.h>

#define WAVE 64

// ---------------------------------------------------------------------------
// K1: type_idx[b] = argmax_k typeTensor[b*K+k]  (first max on ties)
// one wave per bag
// ---------------------------------------------------------------------------
__global__ __launch_bounds__(256) void k_argmax(const float* __restrict__ tt,
                                                int* __restrict__ type_idx,
                                                int B, int K) {
    int wid  = threadIdx.x >> 6;
    int lane = threadIdx.x & 63;
    int b = blockIdx.x * (blockDim.x >> 6) + wid;
    if (b >= B) return;
    float best = -INFINITY;
    int   bi   = 0x7fffffff;
    for (int k = lane; k < K; k += WAVE) {
        float v = tt[(size_t)b * K + k];
        if (v > best) { best = v; bi = k; }
    }
    for (int off = 32; off > 0; off >>= 1) {
        float ov = __shfl_down(best, off);
        int   oi = __shfl_down(bi, off);
        if (ov > best || (ov == best && oi < bi)) { best = ov; bi = oi; }
    }
    if (lane == 0) type_idx[b] = bi;
}

// ---------------------------------------------------------------------------
// K2: bag_id[m] = largest b with scope[b] <= m   (binary search, scope[B]=M)
// ---------------------------------------------------------------------------
__global__ __launch_bounds__(256) void k_bagid(const int* __restrict__ scope,
                                               int* __restrict__ bag_id,
                                               int M, int B) {
    int m = blockIdx.x * blockDim.x + threadIdx.x;
    if (m >= M) return;
    int lo = 0, hi = B; // scope has B+1 entries
    while (hi - lo > 1) {
        int mid = (lo + hi) >> 1;
        if (scope[mid] <= m) lo = mid; else hi = mid;
    }
    bag_id[m] = lo;
}

// ---------------------------------------------------------------------------
// K3: per-mention mean embedding + selected score.
// One WAVE per mention; lane holds float4 of the D=256 row (64*4 = 256).
// men_emb[m][:] = mean over tokens; sel[m] = dot(men_emb[m], W[type_idx[bag]])
// ---------------------------------------------------------------------------
__global__ __launch_bounds__(256) void k_mention(const int* __restrict__ fs,
                                                 const int* __restrict__ offs,
                                                 const int* __restrict__ bag_id,
                                                 const int* __restrict__ type_idx,
                                                 const float* __restrict__ we,
                                                 const float* __restrict__ lw,
                                                 float* __restrict__ men_emb,
                                                 float* __restrict__ sel,
                                                 int M, int T, int D) {
    int wid  = threadIdx.x >> 6;
    int lane = threadIdx.x & 63;
    int m = blockIdx.x * (blockDim.x >> 6) + wid;
    if (m >= M) return;

    int t0 = offs[m];
    int t1 = (m + 1 < M) ? offs[m + 1] : T;
    int dstride = D >> 2;                       // float4 per row (== 64)

    const float4* we4 = (const float4*)we;
    float4 acc = make_float4(0.f, 0.f, 0.f, 0.f);

    int t = t0;
    for (; t + 1 < t1; t += 2) {                // 2-way unroll: 2 loads in flight
        int v0 = fs[t];
        int v1 = fs[t + 1];
        float4 a = we4[(size_t)v0 * dstride + lane];
        float4 b = we4[(size_t)v1 * dstride + lane];
        acc.x += a.x + b.x;
        acc.y += a.y + b.y;
        acc.z += a.z + b.z;
        acc.w += a.w + b.w;
    }
    if (t < t1) {
        int v0 = fs[t];
        float4 a = we4[(size_t)v0 * dstride + lane];
        acc.x += a.x; acc.y += a.y; acc.z += a.z; acc.w += a.w;
    }

    int cnt = t1 - t0;
    float inv = (cnt > 0) ? (1.0f / (float)cnt) : 0.0f;
    float4 me = make_float4(acc.x * inv, acc.y * inv, acc.z * inv, acc.w * inv);

    ((float4*)men_emb)[(size_t)m * dstride + lane] = me;

    int r = type_idx[bag_id[m]];
    const float4* lw4 = (const float4*)lw;
    float4 w = lw4[(size_t)r * dstride + lane];
    float p = me.x * w.x + me.y * w.y + me.z * w.z + me.w * w.w;
    for (int off = 32; off > 0; off >>= 1) p += __shfl_down(p, off);
    if (lane == 0) sel[m] = p;
}

// ---------------------------------------------------------------------------
// K4: per-bag online softmax over sel, attention-weighted sum of men_emb,
// then projection out[b][k] = dot(bag_emb, W[k]).  One 256-block per bag.
// ---------------------------------------------------------------------------
__global__ __launch_bounds__(256) void k_bag(const int* __restrict__ scope,
                                             const float* __restrict__ sel,
                                             const float* __restrict__ men_emb,
                                             const float* __restrict__ lw,
                                             float* __restrict__ out,
                                             int D, int K) {
    int b   = blockIdx.x;
    int tid = threadIdx.x;
    int m0 = scope[b];
    int m1 = scope[b + 1];
    int n  = m1 - m0;

    __shared__ float red[8];
    __shared__ float s_stat[2];
    __shared__ float s_att[256];
    __shared__ float s_be[256];

    // ---- 1) max over sel in bag ----
    float mx = -INFINITY;
    for (int i = tid; i < n; i += blockDim.x) mx = fmaxf(mx, sel[m0 + i]);
    for (int off = 32; off > 0; off >>= 1) mx = fmaxf(mx, __shfl_down(mx, off));
    if ((tid & 63) == 0) red[tid >> 6] = mx;
    __syncthreads();
    if (tid == 0) {
        float v = red[0];
        for (int wv = 1; wv < (int)(blockDim.x >> 6); ++wv) v = fmaxf(v, red[wv]);
        s_stat[0] = v;
    }
    __syncthreads();
    mx = s_stat[0];

    // ---- 2) sum of exp ----
    float se = 0.f;
    for (int i = tid; i < n; i += blockDim.x) se += expf(sel[m0 + i] - mx);
    for (int off = 32; off > 0; off >>= 1) se += __shfl_down(se, off);
    if ((tid & 63) == 0) red[tid >> 6] = se;
    __syncthreads();
    if (tid == 0) {
        float v = 0.f;
        for (int wv = 0; wv < (int)(blockDim.x >> 6); ++wv) v += red[wv];
        s_stat[1] = (v > 0.f) ? (1.0f / v) : 0.0f;
    }
    __syncthreads();
    float inv_se = s_stat[1];

    // ---- 3) bag_emb[d] = sum_m att[m] * men_emb[m][d]; thread tid owns dim tid
    float be = 0.f;
    for (int base = 0; base < n; base += blockDim.x) {
        int c = min((int)blockDim.x, n - base);
        if (tid < c) s_att[tid] = expf(sel[m0 + base + tid] - mx) * inv_se;
        __syncthreads();
        if (tid < D) {
            for (int j = 0; j < c; ++j)
                be += s_att[j] * men_emb[(size_t)(m0 + base + j) * D + tid];
        }
        __syncthreads();
    }
    if (tid < D) s_be[tid] = be;
    __syncthreads();

    // ---- 4) projection: out[b][k] = dot(s_be, W[k]) ----
    for (int k = tid; k < K; k += blockDim.x) {
        const float4* wr4 = (const float4*)(lw + (size_t)k * D);
        float o = 0.f;
        int d4n = D >> 2;
        for (int d4 = 0; d4 < d4n; ++d4) {
            float4 w = wr4[d4];
            int d = d4 << 2;
            o += s_be[d] * w.x + s_be[d + 1] * w.y + s_be[d + 2] * w.z + s_be[d + 3] * w.w;
        }
        out[(size_t)b * K + k] = o;
    }
}

// ---------------------------------------------------------------------------
extern "C" void kernel_launch(void* const* d_in, const int* in_sizes, int n_in,
                              void* d_out, int out_size, void* d_ws, size_t ws_size,
                              hipStream_t stream) {
    const int*   feature_seq = (const int*)d_in[0];
    const int*   offset_seq  = (const int*)d_in[1];
    const int*   scope       = (const int*)d_in[2];
    const float* typeTensor  = (const float*)d_in[3];
    const float* word_emb    = (const float*)d_in[4];
    const float* linear_w    = (const float*)d_in[5];
    float* out = (float*)d_out;

    const int T = in_sizes[0];
    const int M = in_sizes[1];
    const int B = in_sizes[2] - 1;
    const int K = in_sizes[3] / B;       // 100
    const int D = in_sizes[5] / K;       // 256

    // workspace carve-up
    char* w = (char*)d_ws;
    auto align256 = [](size_t x) { return (x + 255) & ~(size_t)255; };
    int* type_idx = (int*)w;                 w += align256((size_t)B * sizeof(int));
    int* bag_id   = (int*)w;                 w += align256((size_t)M * sizeof(int));
    float* sel    = (float*)w;               w += align256((size_t)M * sizeof(float));
    float* men_emb = (float*)w;              // M * D floats

    // K1: argmax per bag (4 waves/block -> 4 bags/block)
    {
        int bagsPerBlock = 256 / WAVE;
        int grid = (B + bagsPerBlock - 1) / bagsPerBlock;
        k_argmax<<<grid, 256, 0, stream>>>(typeTensor, type_idx, B, K);
    }
    // K2: bag id per mention
    {
        int grid = (M + 255) / 256;
        k_bagid<<<grid, 256, 0, stream>>>(scope, bag_id, M, B);
    }
    // K3: mention means + selected scores (wave per mention)
    {
        int mentionsPerBlock = 256 / WAVE;
        int grid = (M + mentionsPerBlock - 1) / mentionsPerBlock;
        k_mention<<<grid, 256, 0, stream>>>(feature_seq, offset_seq, bag_id, type_idx,
                                            word_emb, linear_w, men_emb, sel, M, T, D);
    }
    // K4: per-bag softmax + weighted sum + projection
    {
        k_bag<<<B, 256, 0, stream>>>(scope, sel, men_emb, linear_w, out, D, K);
    }
}

// Round 2
// 286.290 us; speedup vs baseline: 1.0652x; 1.0652x over previous
//
#include <hip/hip_runtime.h>
#include <math.h>

#define WAVE 64

// ---------------------------------------------------------------------------
// K1: type_idx[b] = argmax_k typeTensor[b*K+k]  (first max on ties)
// one wave per bag
// ---------------------------------------------------------------------------
__global__ __launch_bounds__(256) void k_argmax(const float* __restrict__ tt,
                                                int* __restrict__ type_idx,
                                                int B, int K) {
    int wid  = threadIdx.x >> 6;
    int lane = threadIdx.x & 63;
    int b = blockIdx.x * (blockDim.x >> 6) + wid;
    if (b >= B) return;
    float best = -INFINITY;
    int   bi   = 0x7fffffff;
    for (int k = lane; k < K; k += WAVE) {
        float v = tt[(size_t)b * K + k];
        if (v > best) { best = v; bi = k; }
    }
    for (int off = 32; off > 0; off >>= 1) {
        float ov = __shfl_down(best, off);
        int   oi = __shfl_down(bi, off);
        if (ov > best || (ov == best && oi < bi)) { best = ov; bi = oi; }
    }
    if (lane == 0) type_idx[b] = bi;
}

// ---------------------------------------------------------------------------
// K2: per-mention mean embedding + selected score. One wave per mention.
// Lane-parallel index prefetch + shfl broadcast + 4-way unrolled row gather.
// bag_id computed inline via binary search on scope (L1-hot, 13 steps).
// ---------------------------------------------------------------------------
__global__ __launch_bounds__(256) void k_mention(const int* __restrict__ fs,
                                                 const int* __restrict__ offs,
                                                 const int* __restrict__ scope,
                                                 const int* __restrict__ type_idx,
                                                 const float* __restrict__ we,
                                                 const float* __restrict__ lw,
                                                 float* __restrict__ men_emb,
                                                 float* __restrict__ sel,
                                                 int M, int T, int B, int D) {
    int wid  = threadIdx.x >> 6;
    int lane = threadIdx.x & 63;
    int m = blockIdx.x * (blockDim.x >> 6) + wid;
    if (m >= M) return;

    int t0 = offs[m];
    int t1 = (m + 1 < M) ? offs[m + 1] : T;
    int dstride = D >> 2;                       // float4 per row (== 64)

    const float4* we4 = (const float4*)we;
    float4 acc = make_float4(0.f, 0.f, 0.f, 0.f);

    for (int base = t0; base < t1; base += WAVE) {
        int nn = min(WAVE, t1 - base);
        // one coalesced load fetches this chunk's token indices
        int myidx = (lane < nn) ? fs[base + lane] : 0;
        int j = 0;
        for (; j + 4 <= nn; j += 4) {
            int i0 = __shfl(myidx, j);
            int i1 = __shfl(myidx, j + 1);
            int i2 = __shfl(myidx, j + 2);
            int i3 = __shfl(myidx, j + 3);
            float4 a = we4[(size_t)i0 * dstride + lane];
            float4 b = we4[(size_t)i1 * dstride + lane];
            float4 c = we4[(size_t)i2 * dstride + lane];
            float4 d = we4[(size_t)i3 * dstride + lane];
            acc.x += (a.x + b.x) + (c.x + d.x);
            acc.y += (a.y + b.y) + (c.y + d.y);
            acc.z += (a.z + b.z) + (c.z + d.z);
            acc.w += (a.w + b.w) + (c.w + d.w);
        }
        for (; j < nn; ++j) {
            int i0 = __shfl(myidx, j);
            float4 a = we4[(size_t)i0 * dstride + lane];
            acc.x += a.x; acc.y += a.y; acc.z += a.z; acc.w += a.w;
        }
    }

    int cnt = t1 - t0;
    float inv = 1.0f / (float)cnt;
    float4 me = make_float4(acc.x * inv, acc.y * inv, acc.z * inv, acc.w * inv);

    ((float4*)men_emb)[(size_t)m * dstride + lane] = me;

    // bag_id: largest b with scope[b] <= m (scope cached, all lanes redundant)
    int lo = 0, hi = B;
    while (hi - lo > 1) {
        int mid = (lo + hi) >> 1;
        if (scope[mid] <= m) lo = mid; else hi = mid;
    }
    int r = type_idx[lo];

    const float4* lw4 = (const float4*)lw;
    float4 w = lw4[(size_t)r * dstride + lane];
    float p = me.x * w.x + me.y * w.y + me.z * w.z + me.w * w.w;
    for (int off = 32; off > 0; off >>= 1) p += __shfl_down(p, off);
    if (lane == 0) sel[m] = p;
}

// ---------------------------------------------------------------------------
// K3: wave per bag: softmax over sel, weighted sum of men_emb rows into
// register float4 (lane owns 4 dims), projection via 100 coalesced W-row
// loads + butterfly dot-reduce. No LDS, no __syncthreads.
// ---------------------------------------------------------------------------
__global__ __launch_bounds__(256) void k_bag(const int* __restrict__ scope,
                                             const float* __restrict__ sel,
                                             const float* __restrict__ men_emb,
                                             const float* __restrict__ lw,
                                             float* __restrict__ out,
                                             int B, int D, int K) {
    int wid  = threadIdx.x >> 6;
    int lane = threadIdx.x & 63;
    int b = blockIdx.x * (blockDim.x >> 6) + wid;
    if (b >= B) return;

    int m0 = scope[b];
    int m1 = scope[b + 1];
    int n  = m1 - m0;
    int dstride = D >> 2;

    // ---- softmax stats (butterfly so every lane has them) ----
    float mx = -INFINITY;
    for (int i = lane; i < n; i += WAVE) mx = fmaxf(mx, sel[m0 + i]);
    for (int off = 32; off > 0; off >>= 1) mx = fmaxf(mx, __shfl_xor(mx, off));
    float se = 0.f;
    for (int i = lane; i < n; i += WAVE) se += expf(sel[m0 + i] - mx);
    for (int off = 32; off > 0; off >>= 1) se += __shfl_xor(se, off);
    float inv_se = 1.0f / se;

    // ---- weighted sum of mention embeddings ----
    const float4* me4 = (const float4*)men_emb;
    float4 acc = make_float4(0.f, 0.f, 0.f, 0.f);
    for (int base = 0; base < n; base += WAVE) {
        int nn = min(WAVE, n - base);
        float av = (lane < nn) ? expf(sel[m0 + base + lane] - mx) * inv_se : 0.f;
        int j = 0;
        for (; j + 2 <= nn; j += 2) {
            float a0 = __shfl(av, j);
            float a1 = __shfl(av, j + 1);
            float4 r0 = me4[(size_t)(m0 + base + j)     * dstride + lane];
            float4 r1 = me4[(size_t)(m0 + base + j + 1) * dstride + lane];
            acc.x += a0 * r0.x + a1 * r1.x;
            acc.y += a0 * r0.y + a1 * r1.y;
            acc.z += a0 * r0.z + a1 * r1.z;
            acc.w += a0 * r0.w + a1 * r1.w;
        }
        if (j < nn) {
            float a0 = __shfl(av, j);
            float4 r0 = me4[(size_t)(m0 + base + j) * dstride + lane];
            acc.x += a0 * r0.x; acc.y += a0 * r0.y;
            acc.z += a0 * r0.z; acc.w += a0 * r0.w;
        }
    }

    // ---- projection: out[b][k] = dot(bag_emb, W[k]), W rows L2-hot ----
    const float4* lw4 = (const float4*)lw;
    float* ob = out + (size_t)b * K;
    for (int k = 0; k < K; ++k) {
        float4 w = lw4[(size_t)k * dstride + lane];
        float p = acc.x * w.x + acc.y * w.y + acc.z * w.z + acc.w * w.w;
        for (int off = 32; off > 0; off >>= 1) p += __shfl_down(p, off);
        if (lane == 0) ob[k] = p;
    }
}

// ---------------------------------------------------------------------------
extern "C" void kernel_launch(void* const* d_in, const int* in_sizes, int n_in,
                              void* d_out, int out_size, void* d_ws, size_t ws_size,
                              hipStream_t stream) {
    const int*   feature_seq = (const int*)d_in[0];
    const int*   offset_seq  = (const int*)d_in[1];
    const int*   scope       = (const int*)d_in[2];
    const float* typeTensor  = (const float*)d_in[3];
    const float* word_emb    = (const float*)d_in[4];
    const float* linear_w    = (const float*)d_in[5];
    float* out = (float*)d_out;

    const int T = in_sizes[0];
    const int M = in_sizes[1];
    const int B = in_sizes[2] - 1;
    const int K = in_sizes[3] / B;       // 100
    const int D = in_sizes[5] / K;       // 256

    // workspace carve-up
    char* w = (char*)d_ws;
    auto align256 = [](size_t x) { return (x + 255) & ~(size_t)255; };
    int* type_idx = (int*)w;                 w += align256((size_t)B * sizeof(int));
    float* sel    = (float*)w;               w += align256((size_t)M * sizeof(float));
    float* men_emb = (float*)w;              // M * D floats

    // K1: argmax per bag (4 waves/block -> 4 bags/block)
    {
        int bagsPerBlock = 256 / WAVE;
        int grid = (B + bagsPerBlock - 1) / bagsPerBlock;
        k_argmax<<<grid, 256, 0, stream>>>(typeTensor, type_idx, B, K);
    }
    // K2: mention means + selected scores (wave per mention, inline bag_id)
    {
        int mentionsPerBlock = 256 / WAVE;
        int grid = (M + mentionsPerBlock - 1) / mentionsPerBlock;
        k_mention<<<grid, 256, 0, stream>>>(feature_seq, offset_seq, scope, type_idx,
                                            word_emb, linear_w, men_emb, sel,
                                            M, T, B, D);
    }
    // K3: per-bag softmax + weighted sum + projection (wave per bag)
    {
        int bagsPerBlock = 256 / WAVE;
        int grid = (B + bagsPerBlock - 1) / bagsPerBlock;
        k_bag<<<grid, 256, 0, stream>>>(scope, sel, men_emb, linear_w, out, B, D, K);
    }
}

// Round 3
// 273.288 us; speedup vs baseline: 1.1159x; 1.0476x over previous
//
#include <hip/hip_runtime.h>
#include <math.h>

#define WAVE 64
#define KPAD 128   // padded K for W^T (zero-filled cols K..127)

// ---------------------------------------------------------------------------
// K1 (fused prep):
//  blocks [0, nArgBlk):      type_idx[b] = argmax_k typeTensor[b*K+k], wave/bag
//  blocks [nArgBlk, +32):    WT[d][c] = (c<K) ? W[c][d] : 0   (D=256 x KPAD)
// ---------------------------------------------------------------------------
__global__ __launch_bounds__(256) void k_prep(const float* __restrict__ tt,
                                              const float* __restrict__ lw,
                                              int* __restrict__ type_idx,
                                              float* __restrict__ wt,
                                              int B, int K, int D, int nArgBlk) {
    if ((int)blockIdx.x < nArgBlk) {
        int wid  = threadIdx.x >> 6;
        int lane = threadIdx.x & 63;
        int b = blockIdx.x * (blockDim.x >> 6) + wid;
        if (b >= B) return;
        float best = -INFINITY;
        int   bi   = 0x7fffffff;
        for (int k = lane; k < K; k += WAVE) {
            float v = tt[(size_t)b * K + k];
            if (v > best) { best = v; bi = k; }
        }
        for (int off = 32; off > 0; off >>= 1) {
            float ov = __shfl_down(best, off);
            int   oi = __shfl_down(bi, off);
            if (ov > best || (ov == best && oi < bi)) { best = ov; bi = oi; }
        }
        if (lane == 0) type_idx[b] = bi;
    } else {
        // transpose: D*KPAD elements, 32 blocks x 256 threads x 4 elems
        int bid = blockIdx.x - nArgBlk;
        int base = (bid * 256 + (int)threadIdx.x) * 4;
        int total = D * KPAD;
        for (int i = 0; i < 4; ++i) {
            int e = base + i;
            if (e >= total) break;
            int d = e >> 7;        // / KPAD
            int c = e & (KPAD - 1);
            wt[e] = (c < K) ? lw[(size_t)c * D + d] : 0.0f;
        }
    }
}

// ---------------------------------------------------------------------------
// K2: per-mention mean embedding + selected score. One wave per mention.
// Lane-parallel index prefetch + shfl broadcast + 8-deep row-load pipeline.
// bag_id computed inline via binary search on scope.
// ---------------------------------------------------------------------------
__global__ __launch_bounds__(256) void k_mention(const int* __restrict__ fs,
                                                 const int* __restrict__ offs,
                                                 const int* __restrict__ scope,
                                                 const int* __restrict__ type_idx,
                                                 const float* __restrict__ we,
                                                 const float* __restrict__ lw,
                                                 float* __restrict__ men_emb,
                                                 float* __restrict__ sel,
                                                 int M, int T, int B, int D) {
    int wid  = threadIdx.x >> 6;
    int lane = threadIdx.x & 63;
    int m = blockIdx.x * (blockDim.x >> 6) + wid;
    if (m >= M) return;

    int t0 = offs[m];
    int t1 = (m + 1 < M) ? offs[m + 1] : T;
    int dstride = D >> 2;                       // float4 per row (== 64)

    const float4* we4 = (const float4*)we;
    float4 acc = make_float4(0.f, 0.f, 0.f, 0.f);

    for (int base = t0; base < t1; base += WAVE) {
        int nn = min(WAVE, t1 - base);
        // one coalesced load fetches this chunk's token indices
        int myidx = (lane < nn) ? fs[base + lane] : 0;
        int j = 0;
        for (; j + 8 <= nn; j += 8) {
            int i0 = __shfl(myidx, j);
            int i1 = __shfl(myidx, j + 1);
            int i2 = __shfl(myidx, j + 2);
            int i3 = __shfl(myidx, j + 3);
            int i4 = __shfl(myidx, j + 4);
            int i5 = __shfl(myidx, j + 5);
            int i6 = __shfl(myidx, j + 6);
            int i7 = __shfl(myidx, j + 7);
            float4 a = we4[(size_t)i0 * dstride + lane];
            float4 b = we4[(size_t)i1 * dstride + lane];
            float4 c = we4[(size_t)i2 * dstride + lane];
            float4 d = we4[(size_t)i3 * dstride + lane];
            float4 e = we4[(size_t)i4 * dstride + lane];
            float4 f = we4[(size_t)i5 * dstride + lane];
            float4 g = we4[(size_t)i6 * dstride + lane];
            float4 h = we4[(size_t)i7 * dstride + lane];
            acc.x += ((a.x + b.x) + (c.x + d.x)) + ((e.x + f.x) + (g.x + h.x));
            acc.y += ((a.y + b.y) + (c.y + d.y)) + ((e.y + f.y) + (g.y + h.y));
            acc.z += ((a.z + b.z) + (c.z + d.z)) + ((e.z + f.z) + (g.z + h.z));
            acc.w += ((a.w + b.w) + (c.w + d.w)) + ((e.w + f.w) + (g.w + h.w));
        }
        for (; j + 2 <= nn; j += 2) {
            int i0 = __shfl(myidx, j);
            int i1 = __shfl(myidx, j + 1);
            float4 a = we4[(size_t)i0 * dstride + lane];
            float4 b = we4[(size_t)i1 * dstride + lane];
            acc.x += a.x + b.x;
            acc.y += a.y + b.y;
            acc.z += a.z + b.z;
            acc.w += a.w + b.w;
        }
        if (j < nn) {
            int i0 = __shfl(myidx, j);
            float4 a = we4[(size_t)i0 * dstride + lane];
            acc.x += a.x; acc.y += a.y; acc.z += a.z; acc.w += a.w;
        }
    }

    int cnt = t1 - t0;
    float inv = 1.0f / (float)cnt;
    float4 me = make_float4(acc.x * inv, acc.y * inv, acc.z * inv, acc.w * inv);

    ((float4*)men_emb)[(size_t)m * dstride + lane] = me;

    // bag_id: largest b with scope[b] <= m
    int lo = 0, hi = B;
    while (hi - lo > 1) {
        int mid = (lo + hi) >> 1;
        if (scope[mid] <= m) lo = mid; else hi = mid;
    }
    int r = type_idx[lo];

    const float4* lw4 = (const float4*)lw;
    float4 w = lw4[(size_t)r * dstride + lane];
    float p = me.x * w.x + me.y * w.y + me.z * w.z + me.w * w.w;
    for (int off = 32; off > 0; off >>= 1) p += __shfl_down(p, off);
    if (lane == 0) sel[m] = p;
}

// ---------------------------------------------------------------------------
// K3: wave per bag: softmax over sel, weighted sum of men_emb rows (lane owns
// 4 dims), then projection via W^T:
//   bag_emb -> wave-private LDS (ds_write_b128, no barrier needed),
//   lane l owns out cols {2l, 2l+1}: o += be[d] (LDS bcast) * WT[d][2l..2l+1]
//   (coalesced float2 loads, L1/L2-hot; WT zero-padded to KPAD cols).
// No cross-lane reductions anywhere in the projection.
// ---------------------------------------------------------------------------
__global__ __launch_bounds__(256) void k_bag(const int* __restrict__ scope,
                                             const float* __restrict__ sel,
                                             const float* __restrict__ men_emb,
                                             const float* __restrict__ wt,
                                             float* __restrict__ out,
                                             int B, int D, int K) {
    __shared__ float s_be[4][256];
    int wid  = threadIdx.x >> 6;
    int lane = threadIdx.x & 63;
    int b = blockIdx.x * (blockDim.x >> 6) + wid;
    if (b >= B) return;

    int m0 = scope[b];
    int m1 = scope[b + 1];
    int n  = m1 - m0;
    int dstride = D >> 2;

    // ---- softmax stats (butterfly so every lane has them) ----
    float mx = -INFINITY;
    for (int i = lane; i < n; i += WAVE) mx = fmaxf(mx, sel[m0 + i]);
    for (int off = 32; off > 0; off >>= 1) mx = fmaxf(mx, __shfl_xor(mx, off));
    float se = 0.f;
    for (int i = lane; i < n; i += WAVE) se += expf(sel[m0 + i] - mx);
    for (int off = 32; off > 0; off >>= 1) se += __shfl_xor(se, off);
    float inv_se = 1.0f / se;

    // ---- weighted sum of mention embeddings (lane owns dims 4l..4l+3) ----
    const float4* me4 = (const float4*)men_emb;
    float4 acc = make_float4(0.f, 0.f, 0.f, 0.f);
    for (int base = 0; base < n; base += WAVE) {
        int nn = min(WAVE, n - base);
        float av = (lane < nn) ? expf(sel[m0 + base + lane] - mx) * inv_se : 0.f;
        int j = 0;
        for (; j + 2 <= nn; j += 2) {
            float a0 = __shfl(av, j);
            float a1 = __shfl(av, j + 1);
            float4 r0 = me4[(size_t)(m0 + base + j)     * dstride + lane];
            float4 r1 = me4[(size_t)(m0 + base + j + 1) * dstride + lane];
            acc.x += a0 * r0.x + a1 * r1.x;
            acc.y += a0 * r0.y + a1 * r1.y;
            acc.z += a0 * r0.z + a1 * r1.z;
            acc.w += a0 * r0.w + a1 * r1.w;
        }
        if (j < nn) {
            float a0 = __shfl(av, j);
            float4 r0 = me4[(size_t)(m0 + base + j) * dstride + lane];
            acc.x += a0 * r0.x; acc.y += a0 * r0.y;
            acc.z += a0 * r0.z; acc.w += a0 * r0.w;
        }
    }

    // ---- projection via W^T, no cross-lane reduce ----
    float* be = s_be[wid];
    ((float4*)be)[lane] = acc;            // wave-private: no __syncthreads
    const float2* wt2 = (const float2*)wt;      // [D][KPAD/2] float2
    float2 o = make_float2(0.f, 0.f);
    int kc = lane;                               // float2 column index (2l,2l+1)
    #pragma unroll 4
    for (int d4 = 0; d4 < 64; ++d4) {
        float4 b4 = ((const float4*)be)[d4];     // LDS broadcast read
        int d = d4 << 2;
        float2 w0 = wt2[(size_t)(d + 0) * (KPAD / 2) + kc];
        float2 w1 = wt2[(size_t)(d + 1) * (KPAD / 2) + kc];
        float2 w2 = wt2[(size_t)(d + 2) * (KPAD / 2) + kc];
        float2 w3 = wt2[(size_t)(d + 3) * (KPAD / 2) + kc];
        o.x += b4.x * w0.x + b4.y * w1.x + b4.z * w2.x + b4.w * w3.x;
        o.y += b4.x * w0.y + b4.y * w1.y + b4.z * w2.y + b4.w * w3.y;
    }
    int k0 = kc * 2;
    float* ob = out + (size_t)b * K;
    if (k0 + 1 < K) {
        ((float2*)ob)[kc] = o;            // K even: lanes 0..49
    } else if (k0 < K) {
        ob[k0] = o.x;
    }
}

// ---------------------------------------------------------------------------
extern "C" void kernel_launch(void* const* d_in, const int* in_sizes, int n_in,
                              void* d_out, int out_size, void* d_ws, size_t ws_size,
                              hipStream_t stream) {
    const int*   feature_seq = (const int*)d_in[0];
    const int*   offset_seq  = (const int*)d_in[1];
    const int*   scope       = (const int*)d_in[2];
    const float* typeTensor  = (const float*)d_in[3];
    const float* word_emb    = (const float*)d_in[4];
    const float* linear_w    = (const float*)d_in[5];
    float* out = (float*)d_out;

    const int T = in_sizes[0];
    const int M = in_sizes[1];
    const int B = in_sizes[2] - 1;
    const int K = in_sizes[3] / B;       // 100
    const int D = in_sizes[5] / K;       // 256

    // workspace carve-up
    char* w = (char*)d_ws;
    auto align256 = [](size_t x) { return (x + 255) & ~(size_t)255; };
    int* type_idx  = (int*)w;            w += align256((size_t)B * sizeof(int));
    float* sel     = (float*)w;          w += align256((size_t)M * sizeof(float));
    float* wt      = (float*)w;          w += align256((size_t)D * KPAD * sizeof(float));
    float* men_emb = (float*)w;          // M * D floats

    // K1: argmax per bag + W transpose (fused)
    {
        int bagsPerBlock = 256 / WAVE;
        int nArgBlk = (B + bagsPerBlock - 1) / bagsPerBlock;
        int nTrBlk  = (D * KPAD + 1023) / 1024;   // 256 thr x 4 elems
        k_prep<<<nArgBlk + nTrBlk, 256, 0, stream>>>(typeTensor, linear_w,
                                                     type_idx, wt, B, K, D, nArgBlk);
    }
    // K2: mention means + selected scores (wave per mention, inline bag_id)
    {
        int mentionsPerBlock = 256 / WAVE;
        int grid = (M + mentionsPerBlock - 1) / mentionsPerBlock;
        k_mention<<<grid, 256, 0, stream>>>(feature_seq, offset_seq, scope, type_idx,
                                            word_emb, linear_w, men_emb, sel,
                                            M, T, B, D);
    }
    // K3: per-bag softmax + weighted sum + projection (wave per bag)
    {
        int bagsPerBlock = 256 / WAVE;
        int grid = (B + bagsPerBlock - 1) / bagsPerBlock;
        k_bag<<<grid, 256, 0, stream>>>(scope, sel, men_emb, wt, out, B, D, K);
    }
}

// Round 4
// 251.203 us; speedup vs baseline: 1.2140x; 1.0879x over previous
//
#include <hip/hip_runtime.h>
#include <hip/hip_fp16.h>
#include <math.h>

#define WAVE 64
#define KPAD 128   // padded K for W^T (zero-filled cols K..127)

// ---------------------------------------------------------------------------
// K1 (fused prep):
//  blocks [0, nArgBlk):            type_idx[b] = argmax_k typeTensor[b*K+k]
//  blocks [nArgBlk, +nTrBlk):      WT[d][c] = fp16((c<K) ? W[c][d] : 0)
//  blocks [nArgBlk+nTrBlk, end):   weh = fp16(we)   (grid-strided, 8 elem/thr)
// ---------------------------------------------------------------------------
__global__ __launch_bounds__(256) void k_prep(const float* __restrict__ tt,
                                              const float* __restrict__ lw,
                                              const float* __restrict__ we,
                                              int* __restrict__ type_idx,
                                              __half* __restrict__ wt,
                                              __half* __restrict__ weh,
                                              int B, int K, int D, int V,
                                              int nArgBlk, int nTrBlk) {
    int bx = blockIdx.x;
    if (bx < nArgBlk) {
        int wid  = threadIdx.x >> 6;
        int lane = threadIdx.x & 63;
        int b = bx * (blockDim.x >> 6) + wid;
        if (b >= B) return;
        float best = -INFINITY;
        int   bi   = 0x7fffffff;
        for (int k = lane; k < K; k += WAVE) {
            float v = tt[(size_t)b * K + k];
            if (v > best) { best = v; bi = k; }
        }
        for (int off = 32; off > 0; off >>= 1) {
            float ov = __shfl_down(best, off);
            int   oi = __shfl_down(bi, off);
            if (ov > best || (ov == best && oi < bi)) { best = ov; bi = oi; }
        }
        if (lane == 0) type_idx[b] = bi;
    } else if (bx < nArgBlk + nTrBlk) {
        int bid = bx - nArgBlk;
        int base = (bid * 256 + (int)threadIdx.x) * 4;
        int total = D * KPAD;
        for (int i = 0; i < 4; ++i) {
            int e = base + i;
            if (e >= total) break;
            int d = e >> 7;        // / KPAD
            int c = e & (KPAD - 1);
            wt[e] = (c < K) ? __float2half(lw[(size_t)c * D + d]) : __half(0.0f);
        }
    } else {
        int cid = bx - nArgBlk - nTrBlk;
        long long nConv = (long long)gridDim.x - nArgBlk - nTrBlk;
        size_t n8 = ((size_t)V * D) >> 3;                  // groups of 8 floats
        size_t stride = (size_t)nConv * 256;
        const float4* src = (const float4*)we;
        for (size_t i = (size_t)cid * 256 + threadIdx.x; i < n8; i += stride) {
            float4 v0 = src[i * 2];
            float4 v1 = src[i * 2 + 1];
            __half2 h0 = __float22half2_rn(make_float2(v0.x, v0.y));
            __half2 h1 = __float22half2_rn(make_float2(v0.z, v0.w));
            __half2 h2 = __float22half2_rn(make_float2(v1.x, v1.y));
            __half2 h3 = __float22half2_rn(make_float2(v1.z, v1.w));
            uint4 u;
            u.x = *reinterpret_cast<const unsigned int*>(&h0);
            u.y = *reinterpret_cast<const unsigned int*>(&h1);
            u.z = *reinterpret_cast<const unsigned int*>(&h2);
            u.w = *reinterpret_cast<const unsigned int*>(&h3);
            ((uint4*)weh)[i] = u;
        }
    }
}

// ---------------------------------------------------------------------------
// K2: per-mention mean embedding + selected score. One wave per mention.
// fp16 table: one wave-load (16B/lane) fetches TWO token rows (512B each):
// lanes 0-31 -> token j, lanes 32-63 -> token j+1; lane pair (c, c+32) holds
// the SAME dims 8c..8c+7, merged by one __shfl_xor(.,32) after the loop.
// ---------------------------------------------------------------------------
__global__ __launch_bounds__(256) void k_mention(const int* __restrict__ fs,
                                                 const int* __restrict__ offs,
                                                 const int* __restrict__ scope,
                                                 const int* __restrict__ type_idx,
                                                 const __half* __restrict__ weh,
                                                 const float* __restrict__ lw,
                                                 float* __restrict__ men_emb,
                                                 float* __restrict__ sel,
                                                 int M, int T, int B, int D) {
    int wid  = threadIdx.x >> 6;
    int lane = threadIdx.x & 63;
    int m = blockIdx.x * (blockDim.x >> 6) + wid;
    if (m >= M) return;

    int t0 = offs[m];
    int t1 = (m + 1 < M) ? offs[m + 1] : T;
    int c    = lane & 31;      // 16B-chunk (8 dims) within row
    int hsel = lane >> 5;      // 0: even token of pair, 1: odd token

    const float4* we16 = (const float4*)weh;   // 16B = 8 halves; 32 chunks/row
    float a0=0,a1=0,a2=0,a3=0,a4=0,a5=0,a6=0,a7=0;

#define ACC8(q) { const __half2* hh = (const __half2*)&(q);                 \
        float2 f0=__half22float2(hh[0]), f1=__half22float2(hh[1]);          \
        float2 f2=__half22float2(hh[2]), f3=__half22float2(hh[3]);          \
        a0+=f0.x; a1+=f0.y; a2+=f1.x; a3+=f1.y;                             \
        a4+=f2.x; a5+=f2.y; a6+=f3.x; a7+=f3.y; }
#define ACC8S(q,s) { const __half2* hh = (const __half2*)&(q);              \
        float2 f0=__half22float2(hh[0]), f1=__half22float2(hh[1]);          \
        float2 f2=__half22float2(hh[2]), f3=__half22float2(hh[3]);          \
        a0+=(s)*f0.x; a1+=(s)*f0.y; a2+=(s)*f1.x; a3+=(s)*f1.y;             \
        a4+=(s)*f2.x; a5+=(s)*f2.y; a6+=(s)*f3.x; a7+=(s)*f3.y; }

    for (int base = t0; base < t1; base += WAVE) {
        int nn = min(WAVE, t1 - base);
        int myidx = (lane < nn) ? fs[base + lane] : 0;
        int j = 0;
        for (; j + 8 <= nn; j += 8) {          // 4 pair-loads = 8 tokens in flight
            int r0 = __shfl(myidx, j     + hsel);
            int r1 = __shfl(myidx, j + 2 + hsel);
            int r2 = __shfl(myidx, j + 4 + hsel);
            int r3 = __shfl(myidx, j + 6 + hsel);
            float4 q0 = we16[(size_t)r0 * 32 + c];
            float4 q1 = we16[(size_t)r1 * 32 + c];
            float4 q2 = we16[(size_t)r2 * 32 + c];
            float4 q3 = we16[(size_t)r3 * 32 + c];
            ACC8(q0); ACC8(q1); ACC8(q2); ACC8(q3);
        }
        for (; j < nn; j += 2) {               // pair tail (odd handled by s=0)
            int srcl = j + hsel;
            int rr = __shfl(myidx, (srcl < nn) ? srcl : (nn - 1));
            float s = (srcl < nn) ? 1.0f : 0.0f;
            float4 q = we16[(size_t)rr * 32 + c];
            ACC8S(q, s);
        }
    }
#undef ACC8
#undef ACC8S

    // merge the two half-wave token streams (lane c and c+32 hold same dims)
    a0 += __shfl_xor(a0, 32); a1 += __shfl_xor(a1, 32);
    a2 += __shfl_xor(a2, 32); a3 += __shfl_xor(a3, 32);
    a4 += __shfl_xor(a4, 32); a5 += __shfl_xor(a5, 32);
    a6 += __shfl_xor(a6, 32); a7 += __shfl_xor(a7, 32);

    int cnt = t1 - t0;
    float inv = 1.0f / (float)cnt;
    a0*=inv; a1*=inv; a2*=inv; a3*=inv; a4*=inv; a5*=inv; a6*=inv; a7*=inv;

    // write men_emb (fp32): lanes 0..31 each own dims 8c..8c+7
    if (hsel == 0) {
        float4* mp = (float4*)(men_emb + (size_t)m * D);
        mp[c * 2]     = make_float4(a0, a1, a2, a3);
        mp[c * 2 + 1] = make_float4(a4, a5, a6, a7);
    }

    // bag_id: largest b with scope[b] <= m
    int lo = 0, hi = B;
    while (hi - lo > 1) {
        int mid = (lo + hi) >> 1;
        if (scope[mid] <= m) lo = mid; else hi = mid;
    }
    int r = type_idx[lo];

    const float4* wr = (const float4*)(lw + (size_t)r * D);
    float4 u0 = wr[c * 2];
    float4 u1 = wr[c * 2 + 1];
    float p = a0*u0.x + a1*u0.y + a2*u0.z + a3*u0.w
            + a4*u1.x + a5*u1.y + a6*u1.z + a7*u1.w;
    // halves are duplicates after the 32-xor; reduce within 32 gives total
    for (int off = 16; off > 0; off >>= 1) p += __shfl_xor(p, off);
    if (lane == 0) sel[m] = p;
}

// ---------------------------------------------------------------------------
// K3: wave per bag: softmax over sel, weighted sum of men_emb rows (lane owns
// 4 dims), projection via fp16 W^T (lane kc owns out cols 2kc,2kc+1; LDS
// broadcast of bag_emb; coalesced half2 WT loads; no cross-lane reduce).
// ---------------------------------------------------------------------------
__global__ __launch_bounds__(256) void k_bag(const int* __restrict__ scope,
                                             const float* __restrict__ sel,
                                             const float* __restrict__ men_emb,
                                             const __half* __restrict__ wt,
                                             float* __restrict__ out,
                                             int B, int D, int K) {
    __shared__ float s_be[4][256];
    int wid  = threadIdx.x >> 6;
    int lane = threadIdx.x & 63;
    int b = blockIdx.x * (blockDim.x >> 6) + wid;
    if (b >= B) return;

    int m0 = scope[b];
    int m1 = scope[b + 1];
    int n  = m1 - m0;
    int dstride = D >> 2;

    // ---- softmax stats ----
    float mx = -INFINITY;
    for (int i = lane; i < n; i += WAVE) mx = fmaxf(mx, sel[m0 + i]);
    for (int off = 32; off > 0; off >>= 1) mx = fmaxf(mx, __shfl_xor(mx, off));
    float se = 0.f;
    for (int i = lane; i < n; i += WAVE) se += expf(sel[m0 + i] - mx);
    for (int off = 32; off > 0; off >>= 1) se += __shfl_xor(se, off);
    float inv_se = 1.0f / se;

    // ---- weighted sum of mention embeddings (lane owns dims 4l..4l+3) ----
    const float4* me4 = (const float4*)men_emb;
    float4 acc = make_float4(0.f, 0.f, 0.f, 0.f);
    for (int base = 0; base < n; base += WAVE) {
        int nn = min(WAVE, n - base);
        float av = (lane < nn) ? expf(sel[m0 + base + lane] - mx) * inv_se : 0.f;
        int j = 0;
        for (; j + 2 <= nn; j += 2) {
            float a0 = __shfl(av, j);
            float a1 = __shfl(av, j + 1);
            float4 r0 = me4[(size_t)(m0 + base + j)     * dstride + lane];
            float4 r1 = me4[(size_t)(m0 + base + j + 1) * dstride + lane];
            acc.x += a0 * r0.x + a1 * r1.x;
            acc.y += a0 * r0.y + a1 * r1.y;
            acc.z += a0 * r0.z + a1 * r1.z;
            acc.w += a0 * r0.w + a1 * r1.w;
        }
        if (j < nn) {
            float a0 = __shfl(av, j);
            float4 r0 = me4[(size_t)(m0 + base + j) * dstride + lane];
            acc.x += a0 * r0.x; acc.y += a0 * r0.y;
            acc.z += a0 * r0.z; acc.w += a0 * r0.w;
        }
    }

    // ---- projection via fp16 W^T ----
    float* be = s_be[wid];
    ((float4*)be)[lane] = acc;                  // wave-private: no barrier
    const __half2* wt2 = (const __half2*)wt;    // [D][KPAD/2] half2
    float2 o = make_float2(0.f, 0.f);
    int kc = lane;                              // half2 column index
    #pragma unroll 4
    for (int d4 = 0; d4 < 64; ++d4) {
        float4 b4 = ((const float4*)be)[d4];    // LDS broadcast read
        int d = d4 << 2;
        float2 g0 = __half22float2(wt2[(size_t)(d + 0) * (KPAD / 2) + kc]);
        float2 g1 = __half22float2(wt2[(size_t)(d + 1) * (KPAD / 2) + kc]);
        float2 g2 = __half22float2(wt2[(size_t)(d + 2) * (KPAD / 2) + kc]);
        float2 g3 = __half22float2(wt2[(size_t)(d + 3) * (KPAD / 2) + kc]);
        o.x += b4.x * g0.x + b4.y * g1.x + b4.z * g2.x + b4.w * g3.x;
        o.y += b4.x * g0.y + b4.y * g1.y + b4.z * g2.y + b4.w * g3.y;
    }
    int k0 = kc * 2;
    float* ob = out + (size_t)b * K;
    if (k0 + 1 < K) {
        ((float2*)ob)[kc] = o;
    } else if (k0 < K) {
        ob[k0] = o.x;
    }
}

// ---------------------------------------------------------------------------
extern "C" void kernel_launch(void* const* d_in, const int* in_sizes, int n_in,
                              void* d_out, int out_size, void* d_ws, size_t ws_size,
                              hipStream_t stream) {
    const int*   feature_seq = (const int*)d_in[0];
    const int*   offset_seq  = (const int*)d_in[1];
    const int*   scope       = (const int*)d_in[2];
    const float* typeTensor  = (const float*)d_in[3];
    const float* word_emb    = (const float*)d_in[4];
    const float* linear_w    = (const float*)d_in[5];
    float* out = (float*)d_out;

    const int T = in_sizes[0];
    const int M = in_sizes[1];
    const int B = in_sizes[2] - 1;
    const int K = in_sizes[3] / B;       // 100
    const int D = in_sizes[5] / K;       // 256
    const int V = in_sizes[4] / D;       // 100000

    // workspace carve-up
    char* w = (char*)d_ws;
    auto align256 = [](size_t x) { return (x + 255) & ~(size_t)255; };
    int* type_idx  = (int*)w;            w += align256((size_t)B * sizeof(int));
    float* sel     = (float*)w;          w += align256((size_t)M * sizeof(float));
    __half* wt     = (__half*)w;         w += align256((size_t)D * KPAD * sizeof(__half));
    __half* weh    = (__half*)w;         w += align256((size_t)V * D * sizeof(__half));
    float* men_emb = (float*)w;          // M * D floats

    // K1: argmax per bag + WT fp16 transpose + table fp32->fp16 (fused)
    {
        int bagsPerBlock = 256 / WAVE;
        int nArgBlk = (B + bagsPerBlock - 1) / bagsPerBlock;
        int nTrBlk  = (D * KPAD + 1023) / 1024;
        int nConvBlk = 2048;
        k_prep<<<nArgBlk + nTrBlk + nConvBlk, 256, 0, stream>>>(
            typeTensor, linear_w, word_emb, type_idx, wt, weh,
            B, K, D, V, nArgBlk, nTrBlk);
    }
    // K2: mention means + selected scores (wave per mention, fp16 gather)
    {
        int mentionsPerBlock = 256 / WAVE;
        int grid = (M + mentionsPerBlock - 1) / mentionsPerBlock;
        k_mention<<<grid, 256, 0, stream>>>(feature_seq, offset_seq, scope, type_idx,
                                            weh, linear_w, men_emb, sel,
                                            M, T, B, D);
    }
    // K3: per-bag softmax + weighted sum + projection (wave per bag)
    {
        int bagsPerBlock = 256 / WAVE;
        int grid = (B + bagsPerBlock - 1) / bagsPerBlock;
        k_bag<<<grid, 256, 0, stream>>>(scope, sel, men_emb, wt, out, B, D, K);
    }
}